// Round 6
// baseline (1368.340 us; speedup 1.0000x reference)
//
#include <hip/hip_runtime.h>
#include <math.h>

#define T_N   1000
#define L_N   1024
#define N_B   64
#define PADQ  72           // zero-pad quads at head of each parity array
#define NQ    128          // live quads per parity array
#define LOG2E 1.4426950408889634f
#define LN2   0.6931471805599453f
#define DT_F  0.01f

// ---------------- Kernel A: sinr[n,i] = y_ii / (y_ij + 1) ----------------
__global__ __launch_bounds__(256) void sinr_kernel(const float* __restrict__ powers,
                                                   const float* __restrict__ pathloss,
                                                   float* __restrict__ sinr) {
    __shared__ float row[L_N];
    const int i   = blockIdx.x;
    const int tid = threadIdx.x;
    for (int j = tid; j < L_N; j += 256) row[j] = pathloss[i * L_N + j];
    __syncthreads();
    const float pii  = row[i];
    const int   wv   = tid >> 6;
    const int   lane = tid & 63;
    for (int n = wv * 16; n < wv * 16 + 16; ++n) {
        const float* pr = powers + n * L_N;
        float part = 0.f;
        #pragma unroll
        for (int k = 0; k < L_N / 64; ++k)
            part += row[lane + 64 * k] * pr[lane + 64 * k];
        #pragma unroll
        for (int off = 32; off > 0; off >>= 1)
            part += __shfl_down(part, off, 64);
        if (lane == 0) {
            float yii = pii * pr[i];
            sinr[n * L_N + i] = yii / (part - yii + 1.0f);
        }
    }
}

// acc A (out quad q) += window(H = Q quad(q-c), L = Q quad(q-c-1)) x R = r quad c
#define CH(A, H, L, R) do {                                                                \
    A.x = fmaf((H).x,(R).x,A.x); A.y = fmaf((H).y,(R).x,A.y);                              \
    A.z = fmaf((H).z,(R).x,A.z); A.w = fmaf((H).w,(R).x,A.w);                              \
    A.x = fmaf((L).w,(R).y,A.x); A.y = fmaf((H).x,(R).y,A.y);                              \
    A.z = fmaf((H).y,(R).y,A.z); A.w = fmaf((H).z,(R).y,A.w);                              \
    A.x = fmaf((L).z,(R).z,A.x); A.y = fmaf((L).w,(R).z,A.y);                              \
    A.z = fmaf((H).x,(R).z,A.z); A.w = fmaf((H).y,(R).z,A.w);                              \
    A.x = fmaf((L).y,(R).w,A.x); A.y = fmaf((L).z,(R).w,A.y);                              \
    A.z = fmaf((L).w,(R).w,A.z); A.w = fmaf((H).x,(R).w,A.w);                              \
} while (0)

// ---------------- Kernel B: 4 waves/link, parity-split Q, tap-split heavy ----------------
// Roles (rotated by blockIdx): 0 = light  (out-quads [0,128),  tap-quads [0,128))
//                              1 = H1     (out-quads [128,256), tap-quads [0,84)  -> Q)
//                              2 = H2     (out-quads [128,256), tap-quads [84,166)-> S2)
//                              3 = H3     (out-quads [128,256), tap-quads [166,250)->S3)
// Merge pass folds S2+S3 into Q while other threads generate next step's taps.
__global__ __launch_bounds__(256) void scan_kernel(const float* __restrict__ powers,
                                                   const float* __restrict__ sinr,
                                                   float* __restrict__ partial) {
    __shared__ __align__(16) float p2t[1024];
    __shared__ __align__(16) float QE[2][(PADQ + NQ) * 4];
    __shared__ __align__(16) float QO[2][(PADQ + NQ) * 4];
    __shared__ __align__(16) float rr[1024];
    __shared__ __align__(16) float4 SE2[64], SO2[64], SE3[64], SO3[64];
    __shared__ float sv[N_B];
    __shared__ float tails[N_B];

    const int l    = blockIdx.x;
    const int tid  = threadIdx.x;                        // 0..255
    const int lane = tid & 63;

    // ---- init: 2^t table, pads, sinr staging ----
    {
        float4 v;
        v.x = exp2f(0.01f * (float)(4 * tid + 0));
        v.y = exp2f(0.01f * (float)(4 * tid + 1));
        v.z = exp2f(0.01f * (float)(4 * tid + 2));
        v.w = exp2f(0.01f * (float)(4 * tid + 3));
        *(float4*)&p2t[4 * tid] = v;
    }
    if (tid < N_B) sv[tid] = sinr[tid * L_N + l];
    if (tid < PADQ) {
        const float4 z = make_float4(0.f, 0.f, 0.f, 0.f);
        *(float4*)&QE[0][4 * tid] = z;  *(float4*)&QE[1][4 * tid] = z;
        *(float4*)&QO[0][4 * tid] = z;  *(float4*)&QO[1][4 * tid] = z;
    }
    __syncthreads();

    // ---- Q1 (threads < 128) and r for step 1 (threads >= 128) ----
    if (tid < 128) {
        const float s0l = sv[0] * LOG2E;
        float4 e = make_float4(0.f, 0.f, 0.f, 0.f);
        float4 o = make_float4(0.f, 0.f, 0.f, 0.f);
        if (tid < 125) {
            float4 pe_ = *(const float4*)&p2t[8 * tid];
            float4 po_ = *(const float4*)&p2t[8 * tid + 4];
            e.x = 1.f - exp2f((1.f - pe_.x) * s0l);
            e.y = 1.f - exp2f((1.f - pe_.y) * s0l);
            e.z = 1.f - exp2f((1.f - pe_.z) * s0l);
            e.w = 1.f - exp2f((1.f - pe_.w) * s0l);
            o.x = 1.f - exp2f((1.f - po_.x) * s0l);
            o.y = 1.f - exp2f((1.f - po_.y) * s0l);
            o.z = 1.f - exp2f((1.f - po_.z) * s0l);
            o.w = 1.f - exp2f((1.f - po_.w) * s0l);
        }
        *(float4*)&QE[0][(PADQ + tid) * 4] = e;
        *(float4*)&QO[0][(PADQ + tid) * 4] = o;
        if (tid == 124) tails[0] = o.w;                  // Q1[999]
    } else {
        const float s    = sv[1];
        const float sl   = s * LOG2E;
        const float smul = s * LN2 * DT_F;
        #pragma unroll
        for (int m = 0; m < 2; ++m) {
            const int c     = (tid - 128) + 128 * m;
            const int dbase = 4 * c;
            float4 o = make_float4(0.f, 0.f, 0.f, 0.f);
            if (dbase < T_N) {
                float4 p = *(const float4*)&p2t[996 - dbase];
                o.x = smul * p.w * exp2f((1.f - p.w) * sl);
                o.y = smul * p.z * exp2f((1.f - p.z) * sl);
                o.z = smul * p.y * exp2f((1.f - p.y) * sl);
                o.w = smul * p.x * exp2f((1.f - p.x) * sl);
            }
            *(float4*)&rr[4 * c] = o;
        }
    }
    __syncthreads();

    // ---- role setup ----
    const int rid = ((tid >> 6) + blockIdx.x) & 3;
    const int hv  = rid ? 1 : 0;
    const int c0  = (rid == 2) ? 84 : (rid == 3) ? 166 : 0;   // even
    const int h0  = c0 >> 1;
    const int np  = (rid == 0) ? 64 : (rid == 2) ? 41 : 42;   // pairs
    const int wq  = PADQ + 64 * hv + lane;                    // parity-slot

    int cb = 0;
    for (int n = 1; n < N_B; ++n) {
        const float4* QEc4 = (const float4*)QE[cb];
        const float4* QOc4 = (const float4*)QO[cb];
        float4*       QEn4 = (float4*)QE[cb ^ 1];
        float4*       QOn4 = (float4*)QO[cb ^ 1];
        const float4* r4   = (const float4*)rr;

        float4 aA = make_float4(0.f, 0.f, 0.f, 0.f);     // even out-quad
        float4 aB = make_float4(0.f, 0.f, 0.f, 0.f);     // odd  out-quad

        float4 hi  = QOc4[wq - h0];
        float4 mid = QEc4[wq - h0];
        float4 lo  = QOc4[wq - h0 - 1];
        int we = wq - h0 - 1;                            // next even window slot
        int wo = wq - h0 - 2;                            // next odd  window slot

        #pragma unroll 2
        for (int p = 0; p < np; ++p) {
            float4 N1 = QEc4[we]; --we;
            float4 N2 = QOc4[wo]; --wo;
            float4 r0 = r4[c0 + 2 * p];
            float4 r1 = r4[c0 + 2 * p + 1];
            CH(aB, hi,  mid, r0);
            CH(aA, mid, lo,  r0);
            CH(aB, mid, lo,  r1);
            CH(aA, lo,  N1,  r1);
            hi = lo; mid = N1; lo = N2;
        }

        if (rid < 2)      { QEn4[wq] = aA;  QOn4[wq] = aB; }
        else if (rid == 2){ SE2[lane] = aA; SO2[lane] = aB; }
        else              { SE3[lane] = aA; SO3[lane] = aB; }
        __syncthreads();

        // ---- merge partials (tid<128) || generate next step's taps (tid>=128) ----
        if (tid < 128) {
            const int s = tid & 63;
            if (tid < 64) {
                float4 a = QEn4[PADQ + 64 + s];
                float4 b = SE2[s], c = SE3[s];
                a.x += b.x + c.x; a.y += b.y + c.y;
                a.z += b.z + c.z; a.w += b.w + c.w;
                QEn4[PADQ + 64 + s] = a;
            } else {
                float4 a = QOn4[PADQ + 64 + s];
                float4 b = SO2[s], c = SO3[s];
                a.x += b.x + c.x; a.y += b.y + c.y;
                a.z += b.z + c.z; a.w += b.w + c.w;
                QOn4[PADQ + 64 + s] = a;
                if (s == 60) tails[n] = a.w;             // out-quad 249 elem 3 = out 999
            }
        } else if (n < N_B - 1) {
            const float s    = sv[n + 1];
            const float sl   = s * LOG2E;
            const float smul = s * LN2 * DT_F;
            #pragma unroll
            for (int m = 0; m < 2; ++m) {
                const int c     = (tid - 128) + 128 * m;
                const int dbase = 4 * c;
                float4 o = make_float4(0.f, 0.f, 0.f, 0.f);
                if (dbase < T_N) {
                    float4 p = *(const float4*)&p2t[996 - dbase];
                    o.x = smul * p.w * exp2f((1.f - p.w) * sl);
                    o.y = smul * p.z * exp2f((1.f - p.z) * sl);
                    o.z = smul * p.y * exp2f((1.f - p.y) * sl);
                    o.w = smul * p.x * exp2f((1.f - p.x) * sl);
                }
                *(float4*)&rr[4 * c] = o;
            }
        }
        __syncthreads();
        cb ^= 1;
    }

    // ---- per-link loss contribution ----
    if (tid < N_B) {
        float tl   = tails[tid];
        float term = (tid < N_B - 1) ? tl * (powers[(tid + 1) * L_N + l] + 1.0f) : tl;
        if (tid == 0) term += powers[l] + 1.0f;
        #pragma unroll
        for (int off = 32; off > 0; off >>= 1) term += __shfl_down(term, off, 64);
        if (tid == 0) partial[l] = term;
    }
}

// ---------------- Kernel C: final deterministic reduction ----------------
__global__ __launch_bounds__(256) void reduce_kernel(const float* __restrict__ partial,
                                                     float* __restrict__ out) {
    __shared__ float red[4];
    const int tid = threadIdx.x;
    float v = partial[tid] + partial[tid + 256] + partial[tid + 512] + partial[tid + 768];
    #pragma unroll
    for (int off = 32; off > 0; off >>= 1) v += __shfl_down(v, off, 64);
    if ((tid & 63) == 0) red[tid >> 6] = v;
    __syncthreads();
    if (tid == 0) out[0] = red[0] + red[1] + red[2] + red[3];
}

extern "C" void kernel_launch(void* const* d_in, const int* in_sizes, int n_in,
                              void* d_out, int out_size, void* d_ws, size_t ws_size,
                              hipStream_t stream) {
    const float* powers   = (const float*)d_in[0];
    const float* pathloss = (const float*)d_in[1];
    float* sinr    = (float*)d_ws;            // 64*1024 floats
    float* partial = sinr + N_B * L_N;        // 1024 floats

    sinr_kernel<<<dim3(L_N), dim3(256), 0, stream>>>(powers, pathloss, sinr);
    scan_kernel<<<dim3(L_N), dim3(256), 0, stream>>>(powers, sinr, partial);
    reduce_kernel<<<dim3(1), dim3(256), 0, stream>>>(partial, (float*)d_out);
}

// Round 7
// 1254.175 us; speedup vs baseline: 1.0910x; 1.0910x over previous
//
#include <hip/hip_runtime.h>
#include <math.h>

#define T_N   1000
#define L_N   1024
#define N_B   64
#define PADQ  72           // zero-pad quads at the head of each parity array
#define NQ    128          // live quads per parity array (256 quads total)
#define LOG2E 1.4426950408889634f
#define LN2   0.6931471805599453f
#define DT_F  0.01f

// ---------------- Kernel A: sinr[n,i] = y_ii / (y_ij + 1) ----------------
__global__ __launch_bounds__(256) void sinr_kernel(const float* __restrict__ powers,
                                                   const float* __restrict__ pathloss,
                                                   float* __restrict__ sinr) {
    __shared__ float row[L_N];
    const int i   = blockIdx.x;
    const int tid = threadIdx.x;
    for (int j = tid; j < L_N; j += 256) row[j] = pathloss[i * L_N + j];
    __syncthreads();
    const float pii  = row[i];
    const int   wv   = tid >> 6;
    const int   lane = tid & 63;
    for (int n = wv * 16; n < wv * 16 + 16; ++n) {
        const float* pr = powers + n * L_N;
        float part = 0.f;
        #pragma unroll
        for (int k = 0; k < L_N / 64; ++k)
            part += row[lane + 64 * k] * pr[lane + 64 * k];
        #pragma unroll
        for (int off = 32; off > 0; off >>= 1)
            part += __shfl_down(part, off, 64);
        if (lane == 0) {
            float yii = pii * pr[i];
            sinr[n * L_N + i] = yii / (part - yii + 1.0f);
        }
    }
}

// acc A (out quad q) += window(H = Q quad(q-c), L = Q quad(q-c-1)) x R = r quad c
#define CH(A, H, L, R) do {                                                                \
    A.x = fmaf((H).x,(R).x,A.x); A.y = fmaf((H).y,(R).x,A.y);                              \
    A.z = fmaf((H).z,(R).x,A.z); A.w = fmaf((H).w,(R).x,A.w);                              \
    A.x = fmaf((L).w,(R).y,A.x); A.y = fmaf((H).x,(R).y,A.y);                              \
    A.z = fmaf((H).y,(R).y,A.z); A.w = fmaf((H).z,(R).y,A.w);                              \
    A.x = fmaf((L).z,(R).z,A.x); A.y = fmaf((L).w,(R).z,A.y);                              \
    A.z = fmaf((H).x,(R).z,A.z); A.w = fmaf((H).y,(R).z,A.w);                              \
    A.x = fmaf((L).y,(R).w,A.x); A.y = fmaf((L).z,(R).w,A.y);                              \
    A.z = fmaf((L).w,(R).w,A.z); A.w = fmaf((H).x,(R).w,A.w);                              \
} while (0)

// ---------------- Kernel B: 1 link/block, 2 waves, parity-split Q ----------------
// Lane owns out-quads (B+2l, B+2l+1); even quads in QE, odd in QO. The sliding
// window needs ONE new quad per tap-quad, alternating arrays; all LDS reads are
// contiguous 16B-stride across lanes, addresses linear in the loop counter.
// NEW in R7: explicit one-iteration-ahead register pipeline — window quads AND
// tap quads for pair p+1 are loaded before pair p's 64 FMAs, so every ds_read
// has >=128 cycles of FMA cover (the r0-use-same-iteration stall was ~25%).
__global__ __launch_bounds__(128) void scan_kernel(const float* __restrict__ powers,
                                                   const float* __restrict__ sinr,
                                                   float* __restrict__ partial) {
    __shared__ __align__(16) float p2t[1024];
    __shared__ __align__(16) float QE[2][(PADQ + NQ) * 4];
    __shared__ __align__(16) float QO[2][(PADQ + NQ) * 4];
    __shared__ __align__(16) float rr[1024];
    __shared__ float sv[N_B];
    __shared__ float tails[N_B];

    const int l    = blockIdx.x;
    const int tid  = threadIdx.x;                       // 0..127
    const int lane = tid & 63;
    const int wr   = ((tid >> 6) + blockIdx.x) & 1;     // role: 0 light, 1 heavy

    // 2^t table: 128 threads x 2 quads
    #pragma unroll
    for (int m = 0; m < 2; ++m) {
        const int jq = tid + 128 * m;
        float4 v;
        v.x = exp2f(0.01f * (float)(4 * jq + 0));
        v.y = exp2f(0.01f * (float)(4 * jq + 1));
        v.z = exp2f(0.01f * (float)(4 * jq + 2));
        v.w = exp2f(0.01f * (float)(4 * jq + 3));
        *(float4*)&p2t[4 * jq] = v;
    }
    if (tid < N_B) sv[tid] = sinr[tid * L_N + l];
    if (tid < PADQ) {
        const float4 z = make_float4(0.f, 0.f, 0.f, 0.f);
        *(float4*)&QE[0][4 * tid] = z;  *(float4*)&QE[1][4 * tid] = z;
        *(float4*)&QO[0][4 * tid] = z;  *(float4*)&QO[1][4 * tid] = z;
    }
    __syncthreads();

    // Q1 init: thread t -> quads 2t (QE) and 2t+1 (QO); zero for elements >= 1000
    {
        const float s0l = sv[0] * LOG2E;
        float4 e = make_float4(0.f, 0.f, 0.f, 0.f);
        float4 o = make_float4(0.f, 0.f, 0.f, 0.f);
        if (tid < 125) {
            float4 pe_ = *(const float4*)&p2t[8 * tid];
            float4 po_ = *(const float4*)&p2t[8 * tid + 4];
            e.x = 1.f - exp2f((1.f - pe_.x) * s0l);
            e.y = 1.f - exp2f((1.f - pe_.y) * s0l);
            e.z = 1.f - exp2f((1.f - pe_.z) * s0l);
            e.w = 1.f - exp2f((1.f - pe_.w) * s0l);
            o.x = 1.f - exp2f((1.f - po_.x) * s0l);
            o.y = 1.f - exp2f((1.f - po_.y) * s0l);
            o.z = 1.f - exp2f((1.f - po_.z) * s0l);
            o.w = 1.f - exp2f((1.f - po_.w) * s0l);
        }
        *(float4*)&QE[0][(PADQ + tid) * 4] = e;
        *(float4*)&QO[0][(PADQ + tid) * 4] = o;
        if (tid == 124) tails[0] = o.w;                 // Q1[999]
    }
    __syncthreads();

    const int npairs = wr ? 125 : 64;                   // tap-quads / 2
    const int wq     = PADQ + 64 * wr + lane;           // lane's quad slot

    int cb = 0;
    for (int n = 1; n < N_B; ++n) {
        // taps r[d] = DT * q_n[999-d]; zero for d >= 1000
        {
            const float s    = sv[n];
            const float sl   = s * LOG2E;
            const float smul = s * LN2 * DT_F;
            #pragma unroll
            for (int m = 0; m < 2; ++m) {
                const int c     = tid + 128 * m;
                const int dbase = 4 * c;
                float4 o = make_float4(0.f, 0.f, 0.f, 0.f);
                if (dbase < T_N) {
                    float4 p = *(const float4*)&p2t[996 - dbase];
                    o.x = smul * p.w * exp2f((1.f - p.w) * sl);
                    o.y = smul * p.z * exp2f((1.f - p.z) * sl);
                    o.z = smul * p.y * exp2f((1.f - p.y) * sl);
                    o.w = smul * p.x * exp2f((1.f - p.x) * sl);
                }
                *(float4*)&rr[4 * c] = o;
            }
        }
        __syncthreads();

        const float4* QEc4 = (const float4*)QE[cb];
        const float4* QOc4 = (const float4*)QO[cb];
        float4*       QEn4 = (float4*)QE[cb ^ 1];
        float4*       QOn4 = (float4*)QO[cb ^ 1];
        const float4* r4   = (const float4*)rr;

        float4 aA = make_float4(0.f, 0.f, 0.f, 0.f);    // even out-quad B+2l
        float4 aB = make_float4(0.f, 0.f, 0.f, 0.f);    // odd  out-quad B+2l+1

        // pipeline prologue: window + first window/tap pre-loads
        float4 hi  = QOc4[wq];
        float4 mid = QEc4[wq];
        float4 lo  = QOc4[wq - 1];
        float4 N1  = QEc4[wq - 1];
        float4 N2  = QOc4[wq - 2];
        float4 R0  = r4[0];
        float4 R1  = r4[1];
        int ei = wq - 2;          // prefetch idx: even window quad for next pair
        int oi = wq - 3;          // odd window quad for next pair
        int ri = 2;               // tap quad for next pair

        #pragma unroll 2
        for (int p = 0; p < npairs; ++p) {
            // prefetch pair p+1 (pad/overrun safe: min idx 6 >= 0, max ri 251 < 256)
            float4 P1  = QEc4[ei]; --ei;
            float4 P2  = QOc4[oi]; --oi;
            float4 Pr0 = r4[ri], Pr1 = r4[ri + 1]; ri += 2;

            CH(aB, hi,  mid, R0);    // c = 2p   on odd quad
            CH(aA, mid, lo,  R0);    // c = 2p   on even quad
            CH(aB, mid, lo,  R1);    // c = 2p+1 on odd quad
            CH(aA, lo,  N1,  R1);    // c = 2p+1 on even quad

            hi = lo; mid = N1; lo = N2;
            N1 = P1; N2 = P2; R0 = Pr0; R1 = Pr1;
        }

        QEn4[wq] = aA;
        QOn4[wq] = aB;
        if (wr == 1 && lane == 60) tails[n] = aB.w;     // out quad 249, elem 3 = out[999]
        __syncthreads();
        cb ^= 1;
    }

    // per-link loss contribution (wave 0 of the block)
    if (tid < N_B) {
        float tl   = tails[tid];
        float term = (tid < N_B - 1) ? tl * (powers[(tid + 1) * L_N + l] + 1.0f) : tl;
        if (tid == 0) term += powers[l] + 1.0f;
        #pragma unroll
        for (int off = 32; off > 0; off >>= 1) term += __shfl_down(term, off, 64);
        if (tid == 0) partial[l] = term;
    }
}

// ---------------- Kernel C: final deterministic reduction ----------------
__global__ __launch_bounds__(256) void reduce_kernel(const float* __restrict__ partial,
                                                     float* __restrict__ out) {
    __shared__ float red[4];
    const int tid = threadIdx.x;
    float v = partial[tid] + partial[tid + 256] + partial[tid + 512] + partial[tid + 768];
    #pragma unroll
    for (int off = 32; off > 0; off >>= 1) v += __shfl_down(v, off, 64);
    if ((tid & 63) == 0) red[tid >> 6] = v;
    __syncthreads();
    if (tid == 0) out[0] = red[0] + red[1] + red[2] + red[3];
}

extern "C" void kernel_launch(void* const* d_in, const int* in_sizes, int n_in,
                              void* d_out, int out_size, void* d_ws, size_t ws_size,
                              hipStream_t stream) {
    const float* powers   = (const float*)d_in[0];
    const float* pathloss = (const float*)d_in[1];
    float* sinr    = (float*)d_ws;            // 64*1024 floats
    float* partial = sinr + N_B * L_N;        // 1024 floats

    sinr_kernel<<<dim3(L_N), dim3(256), 0, stream>>>(powers, pathloss, sinr);
    scan_kernel<<<dim3(L_N), dim3(128), 0, stream>>>(powers, sinr, partial);
    reduce_kernel<<<dim3(1), dim3(256), 0, stream>>>(partial, (float*)d_out);
}

// Round 8
// 1131.280 us; speedup vs baseline: 1.2096x; 1.1086x over previous
//
#include <hip/hip_runtime.h>
#include <math.h>

#define T_N   1000
#define L_N   1024
#define N_B   64
#define PADU  288          // zero-pad u32s (f16-pairs) below live P region
#define LOG2E 1.4426950408889634f
#define LN2   0.6931471805599453f
#define DT_F  0.01f

typedef unsigned int u32;
typedef _Float16 h2_t __attribute__((ext_vector_type(2)));

__device__ __forceinline__ float dot2f(u32 t, u32 w, float c) {
#if __has_builtin(__builtin_amdgcn_fdot2)
    return __builtin_amdgcn_fdot2(__builtin_bit_cast(h2_t, t),
                                  __builtin_bit_cast(h2_t, w), c, false);
#else
    h2_t a = __builtin_bit_cast(h2_t, t), b = __builtin_bit_cast(h2_t, w);
    return fmaf((float)a.x, (float)b.x, fmaf((float)a.y, (float)b.y, c));
#endif
}

__device__ __forceinline__ u32 pk(float lo, float hi) {
    h2_t v; v.x = (_Float16)lo; v.y = (_Float16)hi;
    return __builtin_bit_cast(u32, v);
}

// ---------------- Kernel A: sinr[n,i] = y_ii / (y_ij + 1) ----------------
__global__ __launch_bounds__(256) void sinr_kernel(const float* __restrict__ powers,
                                                   const float* __restrict__ pathloss,
                                                   float* __restrict__ sinr) {
    __shared__ float row[L_N];
    const int i   = blockIdx.x;
    const int tid = threadIdx.x;
    for (int j = tid; j < L_N; j += 256) row[j] = pathloss[i * L_N + j];
    __syncthreads();
    const float pii  = row[i];
    const int   wv   = tid >> 6;
    const int   lane = tid & 63;
    for (int n = wv * 16; n < wv * 16 + 16; ++n) {
        const float* pr = powers + n * L_N;
        float part = 0.f;
        #pragma unroll
        for (int k = 0; k < L_N / 64; ++k)
            part += row[lane + 64 * k] * pr[lane + 64 * k];
        #pragma unroll
        for (int off = 32; off > 0; off >>= 1)
            part += __shfl_down(part, off, 64);
        if (lane == 0) {
            float yii = pii * pr[i];
            sinr[n * L_N + i] = yii / (part - yii + 1.0f);
        }
    }
}

// 8 dot2: outputs j0..j0+7 against one tap pair (TE) and its shifted twin (TO)
#define D8(W0, W1, W2, W3, TE, TO) do {                                      \
    a0 = dot2f(TE, W0, a0); a1 = dot2f(TO, W0, a1);                          \
    a2 = dot2f(TE, W1, a2); a3 = dot2f(TO, W1, a3);                          \
    a4 = dot2f(TE, W2, a4); a5 = dot2f(TO, W2, a5);                          \
    a6 = dot2f(TE, W3, a6); a7 = dot2f(TO, W3, a7);                          \
} while (0)

// ---------------- Kernel B: 2 waves/link, f16 dot2 conv scan ----------------
// P[m] = f16x2 (lo=Q[2m], hi=Q[2m-1]); T[p] = f16x2 (lo=r[2p], hi=r[2p+1]).
// Even out j: acc += dot2(T[p], P[j/2-p]); odd j+1: same window word, taps
// shifted by one (alignbit). 1 window b128 + 1 tap-broadcast b128 per 4 taps.
__global__ __launch_bounds__(128) void scan_kernel(const float* __restrict__ powers,
                                                   const float* __restrict__ sinr,
                                                   float* __restrict__ partial) {
    __shared__ __align__(16) float p2t[1024];
    __shared__ __align__(16) u32 P[2][PADU + 512];
    __shared__ __align__(16) u32 T[512];
    __shared__ float sv[N_B];
    __shared__ float tails[N_B];
    __shared__ u32 bridge;   // f16 bits of Q[511] (light wave lane 63's out)

    const int l    = blockIdx.x;
    const int tid  = threadIdx.x;                 // 0..127
    const int lane = tid & 63;
    const int wr   = ((tid >> 6) ^ (blockIdx.x & 1) ^ ((blockIdx.x >> 3) & 1)) & 1;

    // 2^t table (f32): 128 threads x 2 quads
    #pragma unroll
    for (int m = 0; m < 2; ++m) {
        const int jq = tid + 128 * m;
        float4 v;
        v.x = exp2f(0.01f * (float)(4 * jq + 0));
        v.y = exp2f(0.01f * (float)(4 * jq + 1));
        v.z = exp2f(0.01f * (float)(4 * jq + 2));
        v.w = exp2f(0.01f * (float)(4 * jq + 3));
        *(float4*)&p2t[4 * jq] = v;
    }
    if (tid < N_B) sv[tid] = sinr[tid * L_N + l];
    for (int i = tid; i < PADU; i += 128) { P[0][i] = 0; P[1][i] = 0; }
    __syncthreads();

    // ---- init: Q1 -> P[0] (f16 pairs); 9th redundant value avoids shfl ----
    {
        const float s0l = sv[0] * LOG2E;
        const int j0 = 8 * tid;
        float q[9];
        #pragma unroll
        for (int ii = 0; ii < 9; ++ii) {
            const int j = j0 - 1 + ii;
            float v = 0.f;
            if (j >= 0 && j < T_N) v = 1.f - exp2f((1.f - p2t[j]) * s0l);
            q[ii] = v;
        }
        uint4 w;
        w.x = pk(q[1], q[0]); w.y = pk(q[3], q[2]);
        w.z = pk(q[5], q[4]); w.w = pk(q[7], q[6]);
        *(uint4*)&P[0][PADU + 4 * tid] = w;
        if (tid == 124) tails[0] = q[8];          // Q1[999]
    }
    __syncthreads();

    const int NB = wr ? 126 : 64;                 // 4-tap blocks (p-range)
    const int j0 = 512 * wr + 8 * lane;           // first output of this lane
    const int s4 = j0 >> 3;                       // window quad index

    int cb = 0;
    for (int n = 1; n < N_B; ++n) {
        // ---- phase R: taps T[p] + bridge fix for P[cb][256].hi ----
        if (n >= 2 && wr == 1 && lane == 0)
            ((unsigned short*)&P[cb][PADU + 256])[1] = (unsigned short)bridge;
        {
            const float s    = sv[n];
            const float sl   = s * LOG2E;
            const float smul = s * LN2 * DT_F;
            const int t8 = 8 * tid;               // taps d = t8..t8+7
            uint4 tw = make_uint4(0u, 0u, 0u, 0u);
            if (t8 < T_N) {
                float4 pa = *(const float4*)&p2t[996 - t8];  // q-idx 996..999-t8
                float4 pb = *(const float4*)&p2t[992 - t8];
                float r0 = smul * pa.w * exp2f((1.f - pa.w) * sl);
                float r1 = smul * pa.z * exp2f((1.f - pa.z) * sl);
                float r2 = smul * pa.y * exp2f((1.f - pa.y) * sl);
                float r3 = smul * pa.x * exp2f((1.f - pa.x) * sl);
                float r4 = smul * pb.w * exp2f((1.f - pb.w) * sl);
                float r5 = smul * pb.z * exp2f((1.f - pb.z) * sl);
                float r6 = smul * pb.y * exp2f((1.f - pb.y) * sl);
                float r7 = smul * pb.x * exp2f((1.f - pb.x) * sl);
                tw.x = pk(r0, r1); tw.y = pk(r2, r3);
                tw.z = pk(r4, r5); tw.w = pk(r6, r7);
            }
            *(uint4*)&T[4 * tid] = tw;
        }
        __syncthreads();

        // ---- phase C: conv ----
        const u32*   Pc = &P[cb][PADU];
        const uint4* P4 = (const uint4*)Pc;       // valid for q >= -PADU/4
        const uint4* T4 = (const uint4*)T;

        float a0 = 0.f, a1 = 0.f, a2 = 0.f, a3 = 0.f;
        float a4 = 0.f, a5 = 0.f, a6 = 0.f, a7 = 0.f;

        uint4 wc = P4[s4], wn = P4[s4 - 1];
        uint4 tc = T4[0],  tn = T4[1];

        #pragma unroll 2
        for (int k = 0; k < NB; ++k) {
            uint4 wnn = P4[s4 - k - 2];           // prefetch (pad-safe)
            uint4 tnn = T4[k + 2];                // broadcast (in-bounds: <=127)
            u32 al;
            al = (tc.x >> 16) | (tc.y << 16);     // (r[2p+1], r[2p+2])
            D8(wc.x, wc.y, wc.z, wc.w, tc.x, al);
            al = (tc.y >> 16) | (tc.z << 16);
            D8(wn.w, wc.x, wc.y, wc.z, tc.y, al);
            al = (tc.z >> 16) | (tc.w << 16);
            D8(wn.z, wn.w, wc.x, wc.y, tc.z, al);
            al = (tc.w >> 16) | (tn.x << 16);
            D8(wn.y, wn.z, wn.w, wc.x, tc.w, al);
            wc = wn; wn = wnn; tc = tn; tn = tnn;
        }

        // ---- epilogue: pack to f16 pairs, write P_next ----
        {
            float qm1 = __shfl_up(a7, 1, 64);     // Q[j0-1] from neighbor
            if (lane == 0) qm1 = 0.f;             // light: Q[-1]=0; heavy: fixed via bridge
            float b0 = (j0 + 0 < T_N) ? a0 : 0.f;
            float b1 = (j0 + 1 < T_N) ? a1 : 0.f;
            float b2 = (j0 + 2 < T_N) ? a2 : 0.f;
            float b3 = (j0 + 3 < T_N) ? a3 : 0.f;
            float b4 = (j0 + 4 < T_N) ? a4 : 0.f;
            float b5 = (j0 + 5 < T_N) ? a5 : 0.f;
            float b6 = (j0 + 6 < T_N) ? a6 : 0.f;
            float bm = (j0     <= T_N) ? qm1 : 0.f;
            uint4 w;
            w.x = pk(b0, bm); w.y = pk(b2, b1);
            w.z = pk(b4, b3); w.w = pk(b6, b5);
            *(uint4*)&P[cb ^ 1][PADU + 4 * s4] = w;
            if (wr == 1 && lane == 60) tails[n] = a7;   // out[999]
            if (wr == 0 && lane == 63)
                bridge = (u32)__builtin_bit_cast(unsigned short, (_Float16)a7); // Q[511]
        }
        __syncthreads();
        cb ^= 1;
    }

    // ---- per-link loss contribution (wave 0) ----
    if (tid < N_B) {
        float tl   = tails[tid];
        float term = (tid < N_B - 1) ? tl * (powers[(tid + 1) * L_N + l] + 1.0f) : tl;
        if (tid == 0) term += powers[l] + 1.0f;
        #pragma unroll
        for (int off = 32; off > 0; off >>= 1) term += __shfl_down(term, off, 64);
        if (tid == 0) partial[l] = term;
    }
}

// ---------------- Kernel C: final deterministic reduction ----------------
__global__ __launch_bounds__(256) void reduce_kernel(const float* __restrict__ partial,
                                                     float* __restrict__ out) {
    __shared__ float red[4];
    const int tid = threadIdx.x;
    float v = partial[tid] + partial[tid + 256] + partial[tid + 512] + partial[tid + 768];
    #pragma unroll
    for (int off = 32; off > 0; off >>= 1) v += __shfl_down(v, off, 64);
    if ((tid & 63) == 0) red[tid >> 6] = v;
    __syncthreads();
    if (tid == 0) out[0] = red[0] + red[1] + red[2] + red[3];
}

extern "C" void kernel_launch(void* const* d_in, const int* in_sizes, int n_in,
                              void* d_out, int out_size, void* d_ws, size_t ws_size,
                              hipStream_t stream) {
    const float* powers   = (const float*)d_in[0];
    const float* pathloss = (const float*)d_in[1];
    float* sinr    = (float*)d_ws;            // 64*1024 floats
    float* partial = sinr + N_B * L_N;        // 1024 floats

    sinr_kernel<<<dim3(L_N), dim3(256), 0, stream>>>(powers, pathloss, sinr);
    scan_kernel<<<dim3(L_N), dim3(128), 0, stream>>>(powers, sinr, partial);
    reduce_kernel<<<dim3(1), dim3(256), 0, stream>>>(partial, (float*)d_out);
}

// Round 9
// 115.044 us; speedup vs baseline: 11.8940x; 9.8334x over previous
//
#include <hip/hip_runtime.h>
#include <math.h>

#define T_N   1000
#define L_N   1024
#define N_B   64
#define PADU  288          // zero-pad u32s (f16-pairs) below live P region
#define LOG2E 1.4426950408889634f
#define LN2   0.6931471805599453f
#define DT_F  0.01f
#define KCUT  24.0f        // tap cutoff: q negligible where 2^t*s > KCUT (e^-24)

typedef unsigned int u32;
typedef _Float16 h2_t __attribute__((ext_vector_type(2)));

__device__ __forceinline__ float dot2f(u32 t, u32 w, float c) {
#if __has_builtin(__builtin_amdgcn_fdot2)
    return __builtin_amdgcn_fdot2(__builtin_bit_cast(h2_t, t),
                                  __builtin_bit_cast(h2_t, w), c, false);
#else
    h2_t a = __builtin_bit_cast(h2_t, t), b = __builtin_bit_cast(h2_t, w);
    return fmaf((float)a.x, (float)b.x, fmaf((float)a.y, (float)b.y, c));
#endif
}

__device__ __forceinline__ u32 pk(float lo, float hi) {
    h2_t v; v.x = (_Float16)lo; v.y = (_Float16)hi;
    return __builtin_bit_cast(u32, v);
}

// ---------------- Kernel A: sinr[n,i] = y_ii / (y_ij + 1) ----------------
__global__ __launch_bounds__(256) void sinr_kernel(const float* __restrict__ powers,
                                                   const float* __restrict__ pathloss,
                                                   float* __restrict__ sinr) {
    __shared__ float row[L_N];
    const int i   = blockIdx.x;
    const int tid = threadIdx.x;
    for (int j = tid; j < L_N; j += 256) row[j] = pathloss[i * L_N + j];
    __syncthreads();
    const float pii  = row[i];
    const int   wv   = tid >> 6;
    const int   lane = tid & 63;
    for (int n = wv * 16; n < wv * 16 + 16; ++n) {
        const float* pr = powers + n * L_N;
        float part = 0.f;
        #pragma unroll
        for (int k = 0; k < L_N / 64; ++k)
            part += row[lane + 64 * k] * pr[lane + 64 * k];
        #pragma unroll
        for (int off = 32; off > 0; off >>= 1)
            part += __shfl_down(part, off, 64);
        if (lane == 0) {
            float yii = pii * pr[i];
            sinr[n * L_N + i] = yii / (part - yii + 1.0f);
        }
    }
}

// 8 dot2: outputs j0..j0+7 against one tap pair (TE) and its shifted twin (TO)
#define D8(W0, W1, W2, W3, TE, TO) do {                                      \
    a0 = dot2f(TE, W0, a0); a1 = dot2f(TO, W0, a1);                          \
    a2 = dot2f(TE, W1, a2); a3 = dot2f(TO, W1, a3);                          \
    a4 = dot2f(TE, W2, a4); a5 = dot2f(TO, W2, a5);                          \
    a6 = dot2f(TE, W3, a6); a7 = dot2f(TO, W3, a7);                          \
} while (0)

// ---------------- Kernel B: 2 waves/link, f16 dot2, support-tracked scan ----------------
// P[m] = f16x2 (lo=Q[2m], hi=Q[2m-1]); T[p] = f16x2 (lo=r[2p], hi=r[2p+1]).
// Support tracking: r_n[d] == 0 (in f16) for d < dmin_n = 999 - k*(s_n),
// k* = 100*log2(KCUT/s). Q_n support = [A_n, 999], A_n = A_{n-1} + dmin_n.
// Tap loop starts at k0 = dmin>>3; when A > 999 the link is dead -> break.
__global__ __launch_bounds__(128) void scan_kernel(const float* __restrict__ powers,
                                                   const float* __restrict__ sinr,
                                                   float* __restrict__ partial) {
    __shared__ __align__(16) float p2t[1024];
    __shared__ __align__(16) u32 P[2][PADU + 512];
    __shared__ __align__(16) u32 T[512];
    __shared__ float sv[N_B];
    __shared__ float tails[N_B];
    __shared__ u32 bridge;   // f16 bits of Q[511] (light wave lane 63's out)

    const int l    = blockIdx.x;
    const int tid  = threadIdx.x;                 // 0..127
    const int lane = tid & 63;
    const int wr   = ((tid >> 6) ^ (blockIdx.x & 1) ^ ((blockIdx.x >> 3) & 1)) & 1;

    // 2^t table (f32): 128 threads x 2 quads
    #pragma unroll
    for (int m = 0; m < 2; ++m) {
        const int jq = tid + 128 * m;
        float4 v;
        v.x = exp2f(0.01f * (float)(4 * jq + 0));
        v.y = exp2f(0.01f * (float)(4 * jq + 1));
        v.z = exp2f(0.01f * (float)(4 * jq + 2));
        v.w = exp2f(0.01f * (float)(4 * jq + 3));
        *(float4*)&p2t[4 * jq] = v;
    }
    if (tid < N_B) { sv[tid] = sinr[tid * L_N + l]; tails[tid] = 0.f; }
    for (int i = tid; i < PADU; i += 128) { P[0][i] = 0; P[1][i] = 0; }
    __syncthreads();

    // ---- init: Q1 -> P[0] (f16 pairs) ----
    {
        const float s0l = sv[0] * LOG2E;
        const int j0 = 8 * tid;
        float q[9];
        #pragma unroll
        for (int ii = 0; ii < 9; ++ii) {
            const int j = j0 - 1 + ii;
            float v = 0.f;
            if (j >= 0 && j < T_N) v = 1.f - exp2f((1.f - p2t[j]) * s0l);
            q[ii] = v;
        }
        uint4 w;
        w.x = pk(q[1], q[0]); w.y = pk(q[3], q[2]);
        w.z = pk(q[5], q[4]); w.w = pk(q[7], q[6]);
        *(uint4*)&P[0][PADU + 4 * tid] = w;
        if (tid == 124) tails[0] = q[8];          // Q1[999]
    }
    __syncthreads();

    const int NB = wr ? 126 : 64;                 // 4-tap blocks (p-range)
    const int j0 = 512 * wr + 8 * lane;           // first output of this lane
    const int s4 = j0 >> 3;                       // window quad index

    int A  = 0;                                   // support lower bound of Q
    int cb = 0;
    for (int n = 1; n < N_B; ++n) {
        // ---- support bookkeeping (uniform across block) ----
        const float s = sv[n];
        const int kstar = (int)(100.f * log2f(KCUT / s)) + 1;   // conservative
        int dmin = 999 - kstar; if (dmin < 0) dmin = 0;
        A += dmin;
        if (A > 999) break;                        // link dead: remaining tails = 0
        const int k0 = dmin >> 3;

        // ---- phase R: taps T[p] + bridge fix for P[cb][256].hi ----
        if (n >= 2 && wr == 1 && lane == 0)
            ((unsigned short*)&P[cb][PADU + 256])[1] = (unsigned short)bridge;
        {
            const float sl   = s * LOG2E;
            const float smul = s * LN2 * DT_F;
            const int t8 = 8 * tid;               // taps d = t8..t8+7
            uint4 tw = make_uint4(0u, 0u, 0u, 0u);
            if (t8 < T_N) {
                float4 pa = *(const float4*)&p2t[996 - t8];
                float4 pb = *(const float4*)&p2t[992 - t8];
                float r0 = smul * pa.w * exp2f((1.f - pa.w) * sl);
                float r1 = smul * pa.z * exp2f((1.f - pa.z) * sl);
                float r2 = smul * pa.y * exp2f((1.f - pa.y) * sl);
                float r3 = smul * pa.x * exp2f((1.f - pa.x) * sl);
                float r4 = smul * pb.w * exp2f((1.f - pb.w) * sl);
                float r5 = smul * pb.z * exp2f((1.f - pb.z) * sl);
                float r6 = smul * pb.y * exp2f((1.f - pb.y) * sl);
                float r7 = smul * pb.x * exp2f((1.f - pb.x) * sl);
                tw.x = pk(r0, r1); tw.y = pk(r2, r3);
                tw.z = pk(r4, r5); tw.w = pk(r6, r7);
            }
            *(uint4*)&T[4 * tid] = tw;
        }
        __syncthreads();

        // ---- phase C: conv over tap blocks k0..NB-1 ----
        const u32*   Pc = &P[cb][PADU];
        const uint4* P4 = (const uint4*)Pc;
        const uint4* T4 = (const uint4*)T;

        float a0 = 0.f, a1 = 0.f, a2 = 0.f, a3 = 0.f;
        float a4 = 0.f, a5 = 0.f, a6 = 0.f, a7 = 0.f;

        if (k0 < NB) {
            uint4 wc = P4[s4 - k0], wn = P4[s4 - k0 - 1];
            uint4 tc = T4[k0],      tn = T4[k0 + 1];

            #pragma unroll 2
            for (int k = k0; k < NB; ++k) {
                uint4 wnn = P4[s4 - k - 2];       // prefetch (pad-safe)
                uint4 tnn = T4[k + 2];            // broadcast (<=127 in bounds)
                u32 al;
                al = (tc.x >> 16) | (tc.y << 16);
                D8(wc.x, wc.y, wc.z, wc.w, tc.x, al);
                al = (tc.y >> 16) | (tc.z << 16);
                D8(wn.w, wc.x, wc.y, wc.z, tc.y, al);
                al = (tc.z >> 16) | (tc.w << 16);
                D8(wn.z, wn.w, wc.x, wc.y, tc.z, al);
                al = (tc.w >> 16) | (tn.x << 16);
                D8(wn.y, wn.z, wn.w, wc.x, tc.w, al);
                wc = wn; wn = wnn; tc = tn; tn = tnn;
            }
        }

        // ---- epilogue: pack to f16 pairs, write P_next ----
        {
            float qm1 = __shfl_up(a7, 1, 64);     // Q[j0-1] from neighbor
            if (lane == 0) qm1 = 0.f;             // light: Q[-1]=0; heavy: via bridge
            float b0 = (j0 + 0 < T_N) ? a0 : 0.f;
            float b1 = (j0 + 1 < T_N) ? a1 : 0.f;
            float b2 = (j0 + 2 < T_N) ? a2 : 0.f;
            float b3 = (j0 + 3 < T_N) ? a3 : 0.f;
            float b4 = (j0 + 4 < T_N) ? a4 : 0.f;
            float b5 = (j0 + 5 < T_N) ? a5 : 0.f;
            float b6 = (j0 + 6 < T_N) ? a6 : 0.f;
            float bm = (j0     <= T_N) ? qm1 : 0.f;
            uint4 w;
            w.x = pk(b0, bm); w.y = pk(b2, b1);
            w.z = pk(b4, b3); w.w = pk(b6, b5);
            *(uint4*)&P[cb ^ 1][PADU + 4 * s4] = w;
            if (wr == 1 && lane == 60) tails[n] = a7;   // out[999]
            if (wr == 0 && lane == 63)
                bridge = (u32)__builtin_bit_cast(unsigned short, (_Float16)a7); // Q[511]
        }
        __syncthreads();
        cb ^= 1;
    }
    __syncthreads();

    // ---- per-link loss contribution (wave 0) ----
    if (tid < N_B) {
        float tl   = tails[tid];
        float term = (tid < N_B - 1) ? tl * (powers[(tid + 1) * L_N + l] + 1.0f) : tl;
        if (tid == 0) term += powers[l] + 1.0f;
        #pragma unroll
        for (int off = 32; off > 0; off >>= 1) term += __shfl_down(term, off, 64);
        if (tid == 0) partial[l] = term;
    }
}

// ---------------- Kernel C: final deterministic reduction ----------------
__global__ __launch_bounds__(256) void reduce_kernel(const float* __restrict__ partial,
                                                     float* __restrict__ out) {
    __shared__ float red[4];
    const int tid = threadIdx.x;
    float v = partial[tid] + partial[tid + 256] + partial[tid + 512] + partial[tid + 768];
    #pragma unroll
    for (int off = 32; off > 0; off >>= 1) v += __shfl_down(v, off, 64);
    if ((tid & 63) == 0) red[tid >> 6] = v;
    __syncthreads();
    if (tid == 0) out[0] = red[0] + red[1] + red[2] + red[3];
}

extern "C" void kernel_launch(void* const* d_in, const int* in_sizes, int n_in,
                              void* d_out, int out_size, void* d_ws, size_t ws_size,
                              hipStream_t stream) {
    const float* powers   = (const float*)d_in[0];
    const float* pathloss = (const float*)d_in[1];
    float* sinr    = (float*)d_ws;            // 64*1024 floats
    float* partial = sinr + N_B * L_N;        // 1024 floats

    sinr_kernel<<<dim3(L_N), dim3(256), 0, stream>>>(powers, pathloss, sinr);
    scan_kernel<<<dim3(L_N), dim3(128), 0, stream>>>(powers, sinr, partial);
    reduce_kernel<<<dim3(1), dim3(256), 0, stream>>>(partial, (float*)d_out);
}

// Round 10
// 57.223 us; speedup vs baseline: 23.9122x; 2.0104x over previous
//
#include <hip/hip_runtime.h>
#include <math.h>

#define T_N   1000
#define L_N   1024
#define N_B   64
#define PADU  288          // zero-pad u32s (f16-pairs) below live P region
#define LOG2E 1.4426950408889634f
#define LN2   0.6931471805599453f
#define DT_F  0.01f
#define KCUT  12.0f        // tap cutoff: q negligible where 2^t*s > KCUT (e^-12)

typedef unsigned int u32;
typedef _Float16 h2_t __attribute__((ext_vector_type(2)));

__device__ __forceinline__ float dot2f(u32 t, u32 w, float c) {
#if __has_builtin(__builtin_amdgcn_fdot2)
    return __builtin_amdgcn_fdot2(__builtin_bit_cast(h2_t, t),
                                  __builtin_bit_cast(h2_t, w), c, false);
#else
    h2_t a = __builtin_bit_cast(h2_t, t), b = __builtin_bit_cast(h2_t, w);
    return fmaf((float)a.x, (float)b.x, fmaf((float)a.y, (float)b.y, c));
#endif
}

__device__ __forceinline__ u32 pk(float lo, float hi) {
    h2_t v; v.x = (_Float16)lo; v.y = (_Float16)hi;
    return __builtin_bit_cast(u32, v);
}

// ---------------- Kernel A: sinr[n,i] = y_ii / (y_ij + 1) ----------------
__global__ __launch_bounds__(256) void sinr_kernel(const float* __restrict__ powers,
                                                   const float* __restrict__ pathloss,
                                                   float* __restrict__ sinr) {
    __shared__ float row[L_N];
    const int i   = blockIdx.x;
    const int tid = threadIdx.x;
    for (int j = tid; j < L_N; j += 256) row[j] = pathloss[i * L_N + j];
    __syncthreads();
    const float pii  = row[i];
    const int   wv   = tid >> 6;
    const int   lane = tid & 63;
    for (int n = wv * 16; n < wv * 16 + 16; ++n) {
        const float* pr = powers + n * L_N;
        float part = 0.f;
        #pragma unroll
        for (int k = 0; k < L_N / 64; ++k)
            part += row[lane + 64 * k] * pr[lane + 64 * k];
        #pragma unroll
        for (int off = 32; off > 0; off >>= 1)
            part += __shfl_down(part, off, 64);
        if (lane == 0) {
            float yii = pii * pr[i];
            sinr[n * L_N + i] = yii / (part - yii + 1.0f);
        }
    }
}

// 8 dot2: outputs j0..j0+7 against one tap pair (TE) and its shifted twin (TO)
#define D8(W0, W1, W2, W3, TE, TO) do {                                      \
    a0 = dot2f(TE, W0, a0); a1 = dot2f(TO, W0, a1);                          \
    a2 = dot2f(TE, W1, a2); a3 = dot2f(TO, W1, a3);                          \
    a4 = dot2f(TE, W2, a4); a5 = dot2f(TO, W2, a5);                          \
    a6 = dot2f(TE, W3, a6); a7 = dot2f(TO, W3, a7);                          \
} while (0)

// ---------------- Kernel B: 2 waves/link, f16 dot2, support-tracked scan ----------------
// P[m] = f16x2 (lo=Q[2m], hi=Q[2m-1]); T[p] = f16x2 (lo=r[2p], hi=r[2p+1]).
// Support tracking: r_n[d] == 0 for d < dmin_n = 999 - k*(s_n), k* = 100*log2(KCUT/s).
// Q_n support = [A_n, 999], A_n = A_{n-1} + dmin_n; dead link (A > 999) -> break.
// Two-sided trip: output j needs taps d <= j - A_prev  ->  kend per wave (exact).
__global__ __launch_bounds__(128) void scan_kernel(const float* __restrict__ powers,
                                                   const float* __restrict__ sinr,
                                                   float* __restrict__ partial) {
    __shared__ __align__(16) float p2t[1024];
    __shared__ __align__(16) u32 P[2][PADU + 512];
    __shared__ __align__(16) u32 T[512];
    __shared__ float sv[N_B];
    __shared__ float tails[N_B];
    __shared__ u32 bridge;   // f16 bits of Q[511] (light wave lane 63's out)

    const int l    = blockIdx.x;
    const int tid  = threadIdx.x;                 // 0..127
    const int lane = tid & 63;
    const int wr   = ((tid >> 6) ^ (blockIdx.x & 1) ^ ((blockIdx.x >> 3) & 1)) & 1;

    // 2^t table (f32): 128 threads x 2 quads
    #pragma unroll
    for (int m = 0; m < 2; ++m) {
        const int jq = tid + 128 * m;
        float4 v;
        v.x = exp2f(0.01f * (float)(4 * jq + 0));
        v.y = exp2f(0.01f * (float)(4 * jq + 1));
        v.z = exp2f(0.01f * (float)(4 * jq + 2));
        v.w = exp2f(0.01f * (float)(4 * jq + 3));
        *(float4*)&p2t[4 * jq] = v;
    }
    if (tid < N_B) { sv[tid] = sinr[tid * L_N + l]; tails[tid] = 0.f; }
    for (int i = tid; i < PADU; i += 128) { P[0][i] = 0; P[1][i] = 0; }
    __syncthreads();

    // ---- init: Q1 -> P[0] (f16 pairs) ----
    {
        const float s0l = sv[0] * LOG2E;
        const int j0 = 8 * tid;
        float q[9];
        #pragma unroll
        for (int ii = 0; ii < 9; ++ii) {
            const int j = j0 - 1 + ii;
            float v = 0.f;
            if (j >= 0 && j < T_N) v = 1.f - exp2f((1.f - p2t[j]) * s0l);
            q[ii] = v;
        }
        uint4 w;
        w.x = pk(q[1], q[0]); w.y = pk(q[3], q[2]);
        w.z = pk(q[5], q[4]); w.w = pk(q[7], q[6]);
        *(uint4*)&P[0][PADU + 4 * tid] = w;
        if (tid == 124) tails[0] = q[8];          // Q1[999]
    }
    __syncthreads();

    const int NB   = wr ? 126 : 64;               // 4-tap blocks (p-range)
    const int j0   = 512 * wr + 8 * lane;         // first output of this lane
    const int s4   = j0 >> 3;                     // window quad index
    const int jmxW = 512 * wr + 511;              // last output of this wave

    int A  = 0;                                   // support lower bound of Q_prev
    int cb = 0;
    for (int n = 1; n < N_B; ++n) {
        // ---- support bookkeeping (uniform across block) ----
        const float s = sv[n];
        const int kstar = (int)(100.f * log2f(KCUT / s)) + 1;   // conservative
        int dmin = 999 - kstar; if (dmin < 0) dmin = 0;
        const int Aprev = A;
        A += dmin;
        if (A > 999) break;                        // link dead: remaining tails = 0
        const int k0 = dmin >> 3;
        // wave-uniform upper tap bound: taps d > jmxW - Aprev hit zeros of Q_prev
        int kend = ((jmxW - Aprev) >> 3) + 1;
        if (kend > NB) kend = NB;

        // ---- phase R: taps T[p] (skip dead quads < k0) + bridge fix ----
        if (n >= 2 && wr == 1 && lane == 0)
            ((unsigned short*)&P[cb][PADU + 256])[1] = (unsigned short)bridge;
        {
            const float sl   = s * LOG2E;
            const float smul = s * LN2 * DT_F;
            const int t8 = 8 * tid;               // taps d = t8..t8+7 (quad idx = tid)
            if (t8 < T_N && tid >= k0) {
                float4 pa = *(const float4*)&p2t[996 - t8];
                float4 pb = *(const float4*)&p2t[992 - t8];
                float r0 = smul * pa.w * exp2f((1.f - pa.w) * sl);
                float r1 = smul * pa.z * exp2f((1.f - pa.z) * sl);
                float r2 = smul * pa.y * exp2f((1.f - pa.y) * sl);
                float r3 = smul * pa.x * exp2f((1.f - pa.x) * sl);
                float r4 = smul * pb.w * exp2f((1.f - pb.w) * sl);
                float r5 = smul * pb.z * exp2f((1.f - pb.z) * sl);
                float r6 = smul * pb.y * exp2f((1.f - pb.y) * sl);
                float r7 = smul * pb.x * exp2f((1.f - pb.x) * sl);
                uint4 tw;
                tw.x = pk(r0, r1); tw.y = pk(r2, r3);
                tw.z = pk(r4, r5); tw.w = pk(r6, r7);
                *(uint4*)&T[4 * tid] = tw;
            } else if (t8 >= T_N) {
                *(uint4*)&T[4 * tid] = make_uint4(0u, 0u, 0u, 0u);
            }
        }
        __syncthreads();

        // ---- phase C: conv over tap blocks k0..kend-1 ----
        const u32*   Pc = &P[cb][PADU];
        const uint4* P4 = (const uint4*)Pc;
        const uint4* T4 = (const uint4*)T;

        float a0 = 0.f, a1 = 0.f, a2 = 0.f, a3 = 0.f;
        float a4 = 0.f, a5 = 0.f, a6 = 0.f, a7 = 0.f;

        if (k0 < kend) {
            uint4 wc = P4[s4 - k0], wn = P4[s4 - k0 - 1];
            uint4 tc = T4[k0],      tn = T4[k0 + 1];

            #pragma unroll 2
            for (int k = k0; k < kend; ++k) {
                uint4 wnn = P4[s4 - k - 2];       // prefetch (pad-safe)
                uint4 tnn = T4[k + 2];            // broadcast (<=127 in bounds)
                u32 al;
                al = (tc.x >> 16) | (tc.y << 16);
                D8(wc.x, wc.y, wc.z, wc.w, tc.x, al);
                al = (tc.y >> 16) | (tc.z << 16);
                D8(wn.w, wc.x, wc.y, wc.z, tc.y, al);
                al = (tc.z >> 16) | (tc.w << 16);
                D8(wn.z, wn.w, wc.x, wc.y, tc.z, al);
                al = (tc.w >> 16) | (tn.x << 16);
                D8(wn.y, wn.z, wn.w, wc.x, tc.w, al);
                wc = wn; wn = wnn; tc = tn; tn = tnn;
            }
        }

        // ---- epilogue: pack to f16 pairs, write P_next ----
        {
            float qm1 = __shfl_up(a7, 1, 64);     // Q[j0-1] from neighbor
            if (lane == 0) qm1 = 0.f;             // light: Q[-1]=0; heavy: via bridge
            float b0 = (j0 + 0 < T_N) ? a0 : 0.f;
            float b1 = (j0 + 1 < T_N) ? a1 : 0.f;
            float b2 = (j0 + 2 < T_N) ? a2 : 0.f;
            float b3 = (j0 + 3 < T_N) ? a3 : 0.f;
            float b4 = (j0 + 4 < T_N) ? a4 : 0.f;
            float b5 = (j0 + 5 < T_N) ? a5 : 0.f;
            float b6 = (j0 + 6 < T_N) ? a6 : 0.f;
            float bm = (j0     <= T_N) ? qm1 : 0.f;
            uint4 w;
            w.x = pk(b0, bm); w.y = pk(b2, b1);
            w.z = pk(b4, b3); w.w = pk(b6, b5);
            *(uint4*)&P[cb ^ 1][PADU + 4 * s4] = w;
            if (wr == 1 && lane == 60) tails[n] = a7;   // out[999]
            if (wr == 0 && lane == 63)
                bridge = (u32)__builtin_bit_cast(unsigned short, (_Float16)a7); // Q[511]
        }
        __syncthreads();
        cb ^= 1;
    }
    __syncthreads();

    // ---- per-link loss contribution (wave 0) ----
    if (tid < N_B) {
        float tl   = tails[tid];
        float term = (tid < N_B - 1) ? tl * (powers[(tid + 1) * L_N + l] + 1.0f) : tl;
        if (tid == 0) term += powers[l] + 1.0f;
        #pragma unroll
        for (int off = 32; off > 0; off >>= 1) term += __shfl_down(term, off, 64);
        if (tid == 0) partial[l] = term;
    }
}

// ---------------- Kernel C: final deterministic reduction ----------------
__global__ __launch_bounds__(256) void reduce_kernel(const float* __restrict__ partial,
                                                     float* __restrict__ out) {
    __shared__ float red[4];
    const int tid = threadIdx.x;
    float v = partial[tid] + partial[tid + 256] + partial[tid + 512] + partial[tid + 768];
    #pragma unroll
    for (int off = 32; off > 0; off >>= 1) v += __shfl_down(v, off, 64);
    if ((tid & 63) == 0) red[tid >> 6] = v;
    __syncthreads();
    if (tid == 0) out[0] = red[0] + red[1] + red[2] + red[3];
}

extern "C" void kernel_launch(void* const* d_in, const int* in_sizes, int n_in,
                              void* d_out, int out_size, void* d_ws, size_t ws_size,
                              hipStream_t stream) {
    const float* powers   = (const float*)d_in[0];
    const float* pathloss = (const float*)d_in[1];
    float* sinr    = (float*)d_ws;            // 64*1024 floats
    float* partial = sinr + N_B * L_N;        // 1024 floats

    sinr_kernel<<<dim3(L_N), dim3(256), 0, stream>>>(powers, pathloss, sinr);
    scan_kernel<<<dim3(L_N), dim3(128), 0, stream>>>(powers, sinr, partial);
    reduce_kernel<<<dim3(1), dim3(256), 0, stream>>>(partial, (float*)d_out);
}